// Round 7
// baseline (476.377 us; speedup 1.0000x reference)
//
#include <hip/hip_runtime.h>
#include <hip/hip_cooperative_groups.h>
#include <stdint.h>

namespace cg = cooperative_groups;

// Problem constants (match reference)
#define HH 512
#define WW 512
#define CC 3
#define KK 32
#define SS 4
#define PP 10
#define NPATCH 126            // (512 + 20 - 32)/4 + 1
#define NP2 (NPATCH * NPATCH) // 15876
#define DD 3072               // C*K*K
#define NMEM 4096
#define THRESHV 0.5f

// ws layout (32-bit words). HARDENING RULE (R4): every word read is
// UNCONDITIONALLY written earlier in the same launch; no single-word flag
// gates conditional writes that are later read.
#define OFF_NORMS  0        // 4096 f:  per-row ||m||^2        (phase A)
#define OFF_PNORM  4096     // 15876 f: per-patch ||u||^2      (phase A)
#define OFF_PMAX   20480    // 1024 f:  per-block output max   (phase C)

__device__ inline float wave_max(float v) {
    for (int off = 32; off; off >>= 1) v = fmaxf(v, __shfl_xor(v, off, 64));
    return v;
}
__device__ inline float wave_min(float v) {
    for (int off = 32; off; off >>= 1) v = fminf(v, __shfl_xor(v, off, 64));
    return v;
}
__device__ inline float wave_sum(float v) {
    for (int off = 32; off; off >>= 1) v += __shfl_xor(v, off, 64);
    return v;
}

// Coverage count along one axis: # patch positions i with i*S <= v+P <= i*S+K-1
__device__ inline int cov1(int v) {
    int pv = v + PP;
    int a = pv - (KK - 1);
    int imin = (a <= 0) ? 0 : ((a + SS - 1) >> 2);
    int imax = pv >> 2;
    if (imax > NPATCH - 1) imax = NPATCH - 1;
    return imax - imin + 1;
}

// Single cooperative kernel, 1024 blocks x 256 threads (4096 waves, fits
// co-residency with ~80 VGPR / ~4.5 KB LDS).
//  A: mem row norms (4 rows/block, 12x float4) + certified fold
//     (out = img*cov_y*cov_x) ; blocks 0..125 also do patch-row column sums
//     -> pnorm.                      [writes norms, pnorm, out]
//  B: every block min/max-reduces norms (L2-hot), certifies its 16 patches
//     via reverse-triangle bound d2 >= (||m||-||u||)^2, cooperatively fixes
//     any uncertified patch exactly (normally zero).
//  C: per-block max of out -> pmax[b] (unconditional).
//  D: every block reduces pmax[0..1023] (L2-hot) and normalizes its slice.
__global__ void mega(const float* __restrict__ mem,
                     const float* __restrict__ img,
                     const float* __restrict__ mem2,
                     const int* __restrict__ mapping,
                     float* __restrict__ norms,
                     float* __restrict__ pnorm,
                     float* __restrict__ pmax,
                     float* __restrict__ out) {
    cg::grid_group grid = cg::this_grid();
    __shared__ float cs[WW];        // phase A: column sums
    __shared__ float red[8];        // cross-wave reductions (4 waves x2)
    __shared__ float smin[256];
    __shared__ int   sarg[256];
    __shared__ uint32_t s_cnt;
    __shared__ uint32_t s_list[16];
    __shared__ float s_lo, s_hi, s_inv;

    int b = blockIdx.x, tid = threadIdx.x;
    int lane = tid & 63, w = tid >> 6;

    // ================= Phase A =================
    // A1: mem norms — rows b*4 .. b*4+3 (one per wave)
    {
        int row = b * 4 + w;
        const float4* rp = (const float4*)(mem + (size_t)row * DD); // 768 f4
        float4 v[12];
#pragma unroll
        for (int i = 0; i < 12; ++i) v[i] = rp[lane + (i << 6)];
        float s0 = 0.f, s1 = 0.f, s2 = 0.f, s3 = 0.f;
#pragma unroll
        for (int i = 0; i < 12; ++i) {
            s0 += v[i].x * v[i].x; s1 += v[i].y * v[i].y;
            s2 += v[i].z * v[i].z; s3 += v[i].w * v[i].w;
        }
        float s = wave_sum((s0 + s1) + (s2 + s3));
        if (lane == 0) norms[row] = s;
    }

    // A2: certified fold — 1024*192 float4 == H*W*C/4
    if (tid < 192) {
        int f = b * 192 + tid;
        float4 v = ((const float4*)img)[f];
        float r[4] = {v.x, v.y, v.z, v.w};
        int e = f * 4;
#pragma unroll
        for (int k = 0; k < 4; ++k) {
            int px = (e + k) / 3;
            int y = px >> 9, x = px & 511;
            float cv = (float)(cov1(y) * cov1(x));
            r[k] *= cv;
        }
        float4 o; o.x = r[0]; o.y = r[1]; o.z = r[2]; o.w = r[3];
        ((float4*)out)[f] = o;
    }

    // A3: patch-row column sums (blocks 0..125 double-duty)
    if (b < NPATCH) {
        int y0 = b * SS - PP;
        float s0 = 0.f, s1 = 0.f;
        int x0c = tid, x1c = tid + 256;
#pragma unroll
        for (int ky = 0; ky < KK; ++ky) {
            int y = y0 + ky;
            if (y >= 0 && y < HH) {
                const float* row = img + (size_t)y * WW * CC;
                const float* p0 = row + x0c * CC;
                const float* p1 = row + x1c * CC;
                s0 += p0[0] * p0[0] + p0[1] * p0[1] + p0[2] * p0[2];
                s1 += p1[0] * p1[0] + p1[1] * p1[1] + p1[2] * p1[2];
            }
        }
        cs[x0c] = s0;
        cs[x1c] = s1;
        __syncthreads();
        if (tid < NPATCH) {
            int x0 = tid * SS - PP;
            float t = 0.f;
#pragma unroll
            for (int kx = 0; kx < KK; ++kx) {
                int xx = x0 + kx;
                if (xx >= 0 && xx < WW) t += cs[xx];
            }
            pnorm[b * NPATCH + tid] = t;
        }
    }

    grid.sync();

    // ================= Phase B: certify + fix =================
    if (tid == 0) s_cnt = 0;
    {
        float mn = INFINITY, mx = -INFINITY;
#pragma unroll
        for (int k = 0; k < 16; ++k) {   // 4096 norms, coalesced, L2-hot
            float v = norms[tid + (k << 8)];
            mn = fminf(mn, v); mx = fmaxf(mx, v);
        }
        mn = wave_min(mn); mx = wave_max(mx);
        if (lane == 0) { red[w] = mn; red[4 + w] = mx; }
    }
    __syncthreads();
    if (tid == 0) {
        s_lo = sqrtf(fminf(fminf(red[0], red[1]), fminf(red[2], red[3])));
        s_hi = sqrtf(fmaxf(fmaxf(red[4], red[5]), fmaxf(red[6], red[7])));
    }
    __syncthreads();
    {
        float lo = s_lo, hi = s_hi;
        int p0 = b * 16;                 // 16 patches per block
        if (tid < 16) {
            int p = p0 + tid;
            if (p < NP2) {
                float un = sqrtf(pnorm[p]);
                float gap = 0.f;
                if (un <= lo) gap = lo - un;
                else if (un >= hi) gap = un - hi;
                if (gap * gap < THRESHV) {
                    uint32_t pos = atomicAdd(&s_cnt, 1u);  // LDS atomic
                    s_list[pos] = (uint32_t)p;
                }
            }
        }
    }
    __syncthreads();
    {
        uint32_t nf = s_cnt;             // block-uniform
        for (uint32_t e = 0; e < nf; ++e) {   // normally nf == 0
            int p = (int)s_list[e];
            int pi = p / NPATCH, pj = p % NPATCH;
            int y0 = pi * SS - PP, x0 = pj * SS - PP;
            float best = INFINITY; int barg = NMEM;
            for (int j = tid; j < NMEM; j += 256) {
                const float* mr = mem + (size_t)j * DD;
                float sacc = 0.f;
                for (int d = 0; d < DD; ++d) {
                    int c = d >> 10, rem = d & 1023;
                    int ky = rem >> 5, kx = rem & 31;
                    int y = y0 + ky, x = x0 + kx;
                    float u = (y >= 0 && y < HH && x >= 0 && x < WW)
                                  ? img[((size_t)y * WW + x) * CC + c] : 0.f;
                    float dif = u - mr[d];
                    sacc += dif * dif;
                }
                if (sacc < best) { best = sacc; barg = j; }
            }
            smin[tid] = best; sarg[tid] = barg;
            __syncthreads();
            for (int stride = 128; stride; stride >>= 1) {
                if (tid < stride) {
                    float s2 = smin[tid + stride];
                    int   a2 = sarg[tid + stride];
                    if (s2 < smin[tid] ||
                        (s2 == smin[tid] && a2 < sarg[tid])) {
                        smin[tid] = s2; sarg[tid] = a2;
                    }
                }
                __syncthreads();
            }
            float dmin = smin[0]; int arg = sarg[0];
            if (dmin < THRESHV) {
                const float* rec = mem2 + (size_t)mapping[arg] * DD;
                for (int d = tid; d < DD; d += 256) {
                    int c = d >> 10, rem = d & 1023;
                    int ky = rem >> 5, kx = rem & 31;
                    int y = y0 + ky, x = x0 + kx;
                    if (y >= 0 && y < HH && x >= 0 && x < WW) {
                        float u = img[((size_t)y * WW + x) * CC + c];
                        atomicAdd(&out[((size_t)y * WW + x) * CC + c],
                                  rec[d] - u);
                    }
                }
            }
            __syncthreads();
        }
    }

    grid.sync();

    // ================= Phase C: per-block output max =================
    {
        float m = -INFINITY;
        if (tid < 192) {
            int f = b * 192 + tid;
            float4 v = ((const float4*)out)[f];
            m = fmaxf(fmaxf(v.x, v.y), fmaxf(v.z, v.w));
        }
        m = wave_max(m);
        if (lane == 0) red[w] = m;
        __syncthreads();
        if (tid == 0)
            pmax[b] = fmaxf(fmaxf(red[0], red[1]), fmaxf(red[2], red[3]));
    }

    grid.sync();

    // ================= Phase D: global max + normalize =================
    {
        float m = -INFINITY;
#pragma unroll
        for (int k = 0; k < 4; ++k)       // 1024 partials, L2-hot
            m = fmaxf(m, pmax[tid + (k << 8)]);
        m = wave_max(m);
        if (lane == 0) red[w] = m;
        __syncthreads();
        if (tid == 0)
            s_inv = 1.0f /
                fmaxf(fmaxf(red[0], red[1]), fmaxf(red[2], red[3]));
        __syncthreads();
        float inv = s_inv;
        if (tid < 192) {
            int f = b * 192 + tid;
            float4 v = ((float4*)out)[f];
            v.x *= inv; v.y *= inv; v.z *= inv; v.w *= inv;
            ((float4*)out)[f] = v;
        }
    }
}

extern "C" void kernel_launch(void* const* d_in, const int* in_sizes, int n_in,
                              void* d_out, int out_size, void* d_ws, size_t ws_size,
                              hipStream_t stream) {
    const float* img     = (const float*)d_in[0];
    const float* mem     = (const float*)d_in[1];
    const float* mem2    = (const float*)d_in[2];
    const int*   mapping = (const int*)d_in[3];
    float* out    = (float*)d_out;
    uint32_t* wsu = (uint32_t*)d_ws;

    float* norms = (float*)(wsu + OFF_NORMS);
    float* pnorm = (float*)(wsu + OFF_PNORM);
    float* pmax  = (float*)(wsu + OFF_PMAX);

    void* args[] = { (void*)&mem, (void*)&img, (void*)&mem2, (void*)&mapping,
                     (void*)&norms, (void*)&pnorm, (void*)&pmax, (void*)&out };
    hipLaunchCooperativeKernel((const void*)mega, dim3(1024), dim3(256),
                               args, 0, stream);
}

// Round 8
// 129.264 us; speedup vs baseline: 3.6853x; 3.6853x over previous
//
#include <hip/hip_runtime.h>
#include <stdint.h>

// Problem constants (match reference)
#define HH 512
#define WW 512
#define CC 3
#define KK 32
#define SS 4
#define PP 10
#define NPATCH 126            // (512 + 20 - 32)/4 + 1
#define NP2 (NPATCH * NPATCH) // 15876
#define DD 3072               // C*K*K
#define NMEM 4096
#define THRESHV 0.5f

// ws layout (32-bit words). HARDENING RULE (R4): every word read by any
// kernel is UNCONDITIONALLY written by an earlier kernel on every launch;
// no single-word flag gates conditional writes that are later read.
// R7 lesson: phase ordering via KERNEL BOUNDARIES, never grid.sync()
// (coop sync ~100us/sync on gfx950 — 8 non-coherent XCD L2 flushes).
#define OFF_NORMS  0        // 4096 f:  per-row ||m||^2        (fused_main)
#define OFF_PNORM  4096     // 15876 f: per-patch ||u||^2      (fused_main)
#define OFF_MODCNT 20480    // 64 u32:  per-block #patches fixed (cert_fix)
#define OFF_PMAXA  36864    // 1024 f:  per-block fold max     (fused_main)

__device__ inline float wave_max(float v) {
    for (int off = 32; off; off >>= 1) v = fmaxf(v, __shfl_xor(v, off, 64));
    return v;
}
__device__ inline float wave_min(float v) {
    for (int off = 32; off; off >>= 1) v = fminf(v, __shfl_xor(v, off, 64));
    return v;
}
__device__ inline float wave_sum(float v) {
    for (int off = 32; off; off >>= 1) v += __shfl_xor(v, off, 64);
    return v;
}

// Coverage count along one axis: # patch positions i with i*S <= v+P <= i*S+K-1
__device__ inline int cov1(int v) {
    int pv = v + PP;
    int a = pv - (KK - 1);
    int imin = (a <= 0) ? 0 : ((a + SS - 1) >> 2);
    int imax = pv >> 2;
    if (imax > NPATCH - 1) imax = NPATCH - 1;
    return imax - imin + 1;
}

// Kernel 1 (1152 blocks x 256):
//  blocks 0..1023  : mem row norms (4 rows/block, 12x float4 unrolled) +
//                    certified fold (out = img * cov_y * cov_x) + pmaxA.
//  blocks 1024..1149: per-patch ||u||^2 for patch-row py=b-1024 via separable
//                    column window-sums (hides under the 48 MB HBM read).
__global__ void fused_main(const float* __restrict__ mem,
                           const float* __restrict__ img,
                           float* __restrict__ norms,
                           float* __restrict__ pnorm,
                           float* __restrict__ pmaxA,
                           float* __restrict__ out) {
    __shared__ float cs[WW];   // patch path: column sums
    __shared__ float smx[4];   // norm path: per-wave maxes
    int b = blockIdx.x, tid = threadIdx.x;
    int lane = tid & 63, w = tid >> 6;

    if (b >= 1024) {
        int py = b - 1024;
        if (py >= NPATCH) return;
        int y0 = py * SS - PP;
        float s0 = 0.f, s1 = 0.f;
        int x0c = tid, x1c = tid + 256;
#pragma unroll
        for (int ky = 0; ky < KK; ++ky) {
            int y = y0 + ky;
            if (y >= 0 && y < HH) {
                const float* row = img + (size_t)y * WW * CC;
                const float* p0 = row + x0c * CC;
                const float* p1 = row + x1c * CC;
                s0 += p0[0] * p0[0] + p0[1] * p0[1] + p0[2] * p0[2];
                s1 += p1[0] * p1[0] + p1[1] * p1[1] + p1[2] * p1[2];
            }
        }
        cs[x0c] = s0;
        cs[x1c] = s1;
        __syncthreads();
        if (tid < NPATCH) {
            int x0 = tid * SS - PP;
            float t = 0.f;
#pragma unroll
            for (int kx = 0; kx < KK; ++kx) {
                int xx = x0 + kx;
                if (xx >= 0 && xx < WW) t += cs[xx];
            }
            pnorm[py * NPATCH + tid] = t;
        }
        return;
    }

    // ---- fold part (threads 0..191; 1024*192 float4 == H*W*C/4) ----
    float m = -INFINITY;
    if (tid < 192) {
        int f = b * 192 + tid;
        float4 v = ((const float4*)img)[f];
        float r[4] = {v.x, v.y, v.z, v.w};
        int e = f * 4;
#pragma unroll
        for (int k = 0; k < 4; ++k) {
            int px = (e + k) / 3;
            int y = px >> 9, x = px & 511;
            float cv = (float)(cov1(y) * cov1(x));
            r[k] *= cv;
            m = fmaxf(m, r[k]);
        }
        float4 o; o.x = r[0]; o.y = r[1]; o.z = r[2]; o.w = r[3];
        ((float4*)out)[f] = o;
    }

    // ---- mem norms (all 4 waves, one row each) ----
    int row = b * 4 + w;
    const float4* rp = (const float4*)(mem + (size_t)row * DD); // 768 f4/row
    float4 v[12];
#pragma unroll
    for (int i = 0; i < 12; ++i) v[i] = rp[lane + (i << 6)];
    float s0 = 0.f, s1 = 0.f, s2 = 0.f, s3 = 0.f;
#pragma unroll
    for (int i = 0; i < 12; ++i) {
        s0 += v[i].x * v[i].x; s1 += v[i].y * v[i].y;
        s2 += v[i].z * v[i].z; s3 += v[i].w * v[i].w;
    }
    float s = wave_sum((s0 + s1) + (s2 + s3));
    if (lane == 0) norms[row] = s;

    // ---- block max -> pmaxA[b] ----
    m = wave_max(m);
    if (lane == 0) smx[w] = m;
    __syncthreads();
    if (tid == 0)
        pmaxA[b] = fmaxf(fmaxf(smx[0], smx[1]), fmaxf(smx[2], smx[3]));
}

// Kernel 2 (64 blocks x 256): certification + exact fallback, fused.
// (a) redundant min/max reduce of the 4096 mem norms (L2-hot, coalesced),
// (b) PARALLEL reverse-triangle bound check of this block's patch slice,
//     failures pushed to an LDS list (capacity 256 >= slice size 249),
// (c) cooperative exact fix for each listed patch (normally zero),
// (d) UNCONDITIONAL write of modcnt[block].
__global__ void cert_fix(const float* __restrict__ img,
                         const float* __restrict__ mem,
                         const float* __restrict__ mem2,
                         const int* __restrict__ mapping,
                         const float* __restrict__ norms,
                         const float* __restrict__ pnorm,
                         float* __restrict__ out,
                         uint32_t* __restrict__ modcnt) {
    __shared__ float rmn[4], rmx[4];
    __shared__ float s_mn, s_mx;
    __shared__ float smin[256];
    __shared__ int   sarg[256];
    __shared__ uint32_t s_cnt;
    __shared__ uint32_t s_list[256];
    __shared__ int   s_mod;
    int tid = threadIdx.x, lane = tid & 63, w = tid >> 6;
    if (tid == 0) { s_mod = 0; s_cnt = 0; }

    // (a) min/max of mem norms (4096 / 256 = 16 per thread, coalesced)
    float mn = INFINITY, mx = -INFINITY;
#pragma unroll
    for (int k = 0; k < 16; ++k) {
        float v = norms[tid + (k << 8)];
        mn = fminf(mn, v); mx = fmaxf(mx, v);
    }
    mn = wave_min(mn); mx = wave_max(mx);
    if (lane == 0) { rmn[w] = mn; rmx[w] = mx; }
    __syncthreads();
    if (tid == 0) {
        s_mn = sqrtf(fminf(fminf(rmn[0], rmn[1]), fminf(rmn[2], rmn[3])));
        s_mx = sqrtf(fmaxf(fmaxf(rmx[0], rmx[1]), fmaxf(rmx[2], rmx[3])));
    }
    __syncthreads();
    float lo = s_mn, hi = s_mx;

    // (b) parallel bound check of this block's slice
    int per = (NP2 + gridDim.x - 1) / gridDim.x;   // 249 @ 64 blocks
    int p0 = blockIdx.x * per;
    int p1 = p0 + per; if (p1 > NP2) p1 = NP2;
    for (int p = p0 + tid; p < p1; p += 256) {
        float un = sqrtf(pnorm[p]);                 // coalesced
        float gap = 0.f;
        if (un <= lo) gap = lo - un;
        else if (un >= hi) gap = un - hi;
        if (gap * gap < THRESHV) {
            uint32_t pos = atomicAdd(&s_cnt, 1u);   // LDS atomic
            s_list[pos] = (uint32_t)p;
        }
    }
    __syncthreads();
    uint32_t nf = s_cnt;                            // block-uniform

    // (c) cooperative exact fix for each failure (normally nf == 0)
    for (uint32_t e = 0; e < nf; ++e) {
        int p = (int)s_list[e];
        int pi = p / NPATCH, pj = p % NPATCH;
        int y0 = pi * SS - PP, x0 = pj * SS - PP;
        float best = INFINITY; int barg = NMEM;
        for (int j = tid; j < NMEM; j += 256) {
            const float* mr = mem + (size_t)j * DD;
            float sacc = 0.f;
            for (int d = 0; d < DD; ++d) {
                int c = d >> 10, rem = d & 1023, ky = rem >> 5, kx = rem & 31;
                int y = y0 + ky, x = x0 + kx;
                float u = (y >= 0 && y < HH && x >= 0 && x < WW)
                              ? img[((size_t)y * WW + x) * CC + c] : 0.f;
                float dif = u - mr[d];
                sacc += dif * dif;
            }
            if (sacc < best) { best = sacc; barg = j; }
        }
        smin[tid] = best; sarg[tid] = barg;
        __syncthreads();
        for (int stride = 128; stride; stride >>= 1) {
            if (tid < stride) {
                float s2 = smin[tid + stride];
                int   a2 = sarg[tid + stride];
                if (s2 < smin[tid] || (s2 == smin[tid] && a2 < sarg[tid])) {
                    smin[tid] = s2; sarg[tid] = a2;
                }
            }
            __syncthreads();
        }
        float dmin = smin[0]; int arg = sarg[0];
        if (dmin < THRESHV) {
            const float* rec = mem2 + (size_t)mapping[arg] * DD;
            for (int d = tid; d < DD; d += 256) {
                int c = d >> 10, rem = d & 1023, ky = rem >> 5, kx = rem & 31;
                int y = y0 + ky, x = x0 + kx;
                if (y >= 0 && y < HH && x >= 0 && x < WW) {
                    float u = img[((size_t)y * WW + x) * CC + c];
                    atomicAdd(&out[((size_t)y * WW + x) * CC + c],
                              rec[d] - u);
                }
            }
            if (tid == 0) s_mod++;
        }
        __syncthreads();
    }
    if (tid == 0) modcnt[blockIdx.x] = (uint32_t)s_mod;  // UNCONDITIONAL
}

// Kernel 3 (1024 blocks x 256): EVERY block independently resolves the
// global max from unconditionally-written data, then normalizes its slice.
//  - modcnt sum == 0 (always, in practice): redundantly reduce the 4 KB
//    L2-hot pmaxA array.
//  - else: redundantly scan the full 3 MB out (correct, slow, never taken).
// All blocks read identical inputs -> identical s_inv; no partial-max
// handoff kernel needed. No conditionally-written word is read.
__global__ void normalize_k(const uint32_t* __restrict__ modcnt,
                            const float* __restrict__ pmaxA,
                            float* __restrict__ out) {
    __shared__ int s_need;
    __shared__ float red[4];
    __shared__ float s_inv;
    int tid = threadIdx.x, lane = tid & 63, w = tid >> 6;
    if (w == 0) {  // first wave sums the 64 mod counts
        int c = (int)modcnt[lane];
        for (int off = 32; off; off >>= 1) c += __shfl_xor(c, off, 64);
        if (lane == 0) s_need = c;
    }
    __syncthreads();
    float m = -INFINITY;
    if (s_need == 0) {                    // block-uniform, grid-consistent
#pragma unroll
        for (int k = 0; k < 4; ++k)       // 1024 partials, L2-hot
            m = fmaxf(m, pmaxA[tid + (k << 8)]);
    } else {
        const float4* o4 = (const float4*)out;
        for (int i = tid; i < (HH * WW * CC) / 4; i += 256) {
            float4 v = o4[i];
            m = fmaxf(m, fmaxf(fmaxf(v.x, v.y), fmaxf(v.z, v.w)));
        }
    }
    m = wave_max(m);
    if (lane == 0) red[w] = m;
    __syncthreads();
    if (tid == 0)
        s_inv = 1.0f / fmaxf(fmaxf(red[0], red[1]), fmaxf(red[2], red[3]));
    __syncthreads();
    float inv = s_inv;
    if (tid < 192) {
        int f = blockIdx.x * 192 + tid;   // 1024*192 float4 == H*W*C/4
        float4 v = ((float4*)out)[f];
        v.x *= inv; v.y *= inv; v.z *= inv; v.w *= inv;
        ((float4*)out)[f] = v;
    }
}

extern "C" void kernel_launch(void* const* d_in, const int* in_sizes, int n_in,
                              void* d_out, int out_size, void* d_ws, size_t ws_size,
                              hipStream_t stream) {
    const float* img     = (const float*)d_in[0];
    const float* mem     = (const float*)d_in[1];
    const float* mem2    = (const float*)d_in[2];
    const int*   mapping = (const int*)d_in[3];
    float* out    = (float*)d_out;
    uint32_t* wsu = (uint32_t*)d_ws;

    float*    norms  = (float*)(wsu + OFF_NORMS);
    float*    pnorm  = (float*)(wsu + OFF_PNORM);
    uint32_t* modcnt = wsu + OFF_MODCNT;
    float*    pmaxA  = (float*)(wsu + OFF_PMAXA);

    fused_main <<<1152, 256, 0, stream>>>(mem, img, norms, pnorm, pmaxA, out);
    cert_fix   <<<64, 256, 0, stream>>>(img, mem, mem2, mapping, norms,
                                        pnorm, out, modcnt);
    normalize_k<<<1024, 256, 0, stream>>>(modcnt, pmaxA, out);
}